// Round 9
// baseline (336.569 us; speedup 1.0000x reference)
//
#include <hip/hip_runtime.h>
#include <hip/hip_bf16.h>
#include <math.h>

// Problem constants
#define NB 16      // batch
#define NA 64      // atoms
#define NC 32      // channels
#define NLVL 4
#define NSLOT 16   // 1+3+5+7 spherical slots
#define NBAS 60

// ws layout (in floats)
#define OFF_REP   0            // 5 * 16*64*16*32 = 5*524288
#define REPSZ     524288
#define OFF_EDGE  2621440      // 16*64*64*4*32 = 8388608
#define OFF_CUT   11010048     // 65536
#define OFF_SPH   11075584     // 1024 rows * 16 * 64 = 1048576
#define OFF_BASIS 12124160     // 1024 rows * 64 * 60 = 3932160
// after levels complete, edge region is dead -> reuse for per-atom partials
#define OFF_PART  OFF_EDGE     // 1024 floats

// ---------------- P1: init rep buffer 0 (a0 into slot 0, zeros elsewhere) ---
__global__ void k_init(const float* __restrict__ oh, const int* __restrict__ chg,
                       const float* __restrict__ Win, const float* __restrict__ bin,
                       float* __restrict__ rep0) {
  int idx = blockIdx.x * 256 + threadIdx.x;           // over 16*64*16*32
  if (idx >= NB * NA * NSLOT * NC) return;
  int c = idx & 31;
  int s = (idx >> 5) & 15;
  int bn = idx >> 9;
  float v = 0.f;
  if (s == 0) {
    float ch = (float)chg[bn] / 9.0f;
    float p1 = ch, p2 = ch * ch;
    v = bin[c];
    #pragma unroll
    for (int sp = 0; sp < 5; sp++) {
      float o = oh[bn * 5 + sp];
      v += o * (Win[(sp * 3 + 0) * 32 + c] + p1 * Win[(sp * 3 + 1) * 32 + c] +
                p2 * Win[(sp * 3 + 2) * 32 + c]);
    }
  }
  rep0[idx] = v;
}

// ---------------- P2: per-edge geometry (cutoff, sph, basis) ----------------
__global__ void k_geom(const float* __restrict__ pos, float* __restrict__ cut,
                       float* __restrict__ sph, float* __restrict__ basis) {
  int row = blockIdx.x;            // b*64 + i
  int j = threadIdx.x;             // 0..63
  int b = row >> 6, i = row & 63;
  float xi = pos[(b * 64 + i) * 3 + 0];
  float yi = pos[(b * 64 + i) * 3 + 1];
  float zi = pos[(b * 64 + i) * 3 + 2];
  float xj = pos[(b * 64 + j) * 3 + 0];
  float yj = pos[(b * 64 + j) * 3 + 1];
  float zj = pos[(b * 64 + j) * 3 + 2];
  float rx = xi - xj, ry = yi - yj, rz = zi - zj;
  float n2 = rx * rx + ry * ry + rz * rz + 1e-12f;
  float r = sqrtf(n2);
  float inv = 1.0f / r;
  float x = rx * inv, y = ry * inv, z = rz * inv;
  float cu = 0.f;
  if (i != j && r > 1e-4f && r < 5.0f)
    cu = 1.0f / (1.0f + expf((r - 3.0f) * 2.0f));
  cut[row * 64 + j] = cu;
  float s[16];
  s[0] = 1.0f;
  s[1] = x; s[2] = y; s[3] = z;
  s[4] = x * y; s[5] = y * z; s[6] = 3.f * z * z - 1.f; s[7] = x * z; s[8] = x * x - y * y;
  s[9]  = y * (3.f * x * x - y * y);
  s[10] = x * y * z;
  s[11] = y * (5.f * z * z - 1.f);
  s[12] = z * (5.f * z * z - 3.f);
  s[13] = x * (5.f * z * z - 1.f);
  s[14] = z * (x * x - y * y);
  s[15] = x * (x * x - 3.f * y * y);
  #pragma unroll
  for (int m = 0; m < 16; m++) sph[(row * 16 + m) * 64 + j] = s[m];
  __shared__ float sb[64 * 60];
  #pragma unroll 4
  for (int k = 0; k < 60; k++) {
    float ck = 5.0f * (float)k / 59.0f;
    float d = r - ck;
    sb[j * 60 + k] = expf(-36.0f * d * d);
  }
  __syncthreads();
  float* dst = basis + row * 3840;
  for (int t = j; t < 3840; t += 64) dst[t] = sb[t];
}

// ---------------- L: one fused message-passing level ------------------------
// Thread mapping: c = tid&31, lidx = (tid>>5)&3, jh = tid>>7 (32 j's each).
// Phase R: rad[32] in registers  = basis(LDS) . W_rad(global, L1-resident)
// Phase A: e = sS(LDS premult s_ij) . W_edge col (32 regs); edge RMW global;
//          msg[7] register accumulate with zero-padded sph.
// LDS ~39.6 KB -> 4 blocks/CU; VGPR target <=128 (launch_bounds 256,4).
__global__ __launch_bounds__(256, 4)
void k_level2(int lvl, const float* __restrict__ Wrad, const float* __restrict__ Wedge,
              const float* __restrict__ Wagg, const float* __restrict__ Wself,
              const float* __restrict__ repPrev, float* __restrict__ repNext,
              float* __restrict__ edge, const float* __restrict__ cut,
              const float* __restrict__ sph, const float* __restrict__ basisG) {
  __shared__ float sBasis[64 * 60];   // 15360 B  [j][k]
  __shared__ float sS[64][32];        //  8192 B  s_ij[d] = rep0_i[d]*rep0_j[d]
  __shared__ float sSphP[4][7][64];   //  7168 B  zero-padded sph
  __shared__ float sCut[64];          //   256 B
  __shared__ float sMsgB[2][4][7][32];//  7168 B  per-jh msg partials
  __shared__ float sMsgS[16][32];     //  2048 B  reduced msg

  int row = blockIdx.x;               // b*64 + i
  int b = row >> 6;
  int i = row & 63;
  int tid = threadIdx.x;
  int c = tid & 31, lidx = (tid >> 5) & 3, jh = tid >> 7;

  // ---- stage ----
  for (int idx = tid; idx < 3840; idx += 256) sBasis[idx] = basisG[row * 3840 + idx];
  const float* repB0 = repPrev + (size_t)(b * 64) * 512;   // rep slot0 of batch b
  const float* repI  = repPrev + (size_t)row * 512;        // rep0_i
  for (int idx = tid; idx < 2048; idx += 256) {
    int j = idx >> 5, d = idx & 31;
    sS[j][d] = repI[d] * repB0[j * 512 + d];
  }
  for (int idx = tid; idx < 1792; idx += 256) {
    int l = idx / 448, rem = idx % 448, m = rem >> 6, j = rem & 63;
    int bs = (l == 0) ? 0 : (l == 1) ? 1 : (l == 2) ? 4 : 9;
    float v = 0.f;
    if (m < 2 * l + 1) v = sph[row * 1024 + (bs + m) * 64 + j];
    sSphP[l][m][j] = v;
  }
  if (tid < 64) sCut[tid] = cut[row * 64 + tid];
  __syncthreads();

  // ---- phase R: rad[jj] for 32 j's of this (lidx, jh) ----
  float rad[32];
  #pragma unroll
  for (int jj = 0; jj < 32; jj++) rad[jj] = 0.f;
  {
    const float* wrp = Wrad + (size_t)((lvl * 4 + lidx) * 60) * 32 + c;
    #pragma unroll 1
    for (int k0 = 0; k0 < 60; k0 += 4) {
      float w0 = wrp[(k0 + 0) * 32];
      float w1 = wrp[(k0 + 1) * 32];
      float w2 = wrp[(k0 + 2) * 32];
      float w3 = wrp[(k0 + 3) * 32];
      #pragma unroll
      for (int jj = 0; jj < 32; jj++) {
        const float4 bv = *(const float4*)&sBasis[(jh * 32 + jj) * 60 + k0];
        rad[jj] += bv.x * w0 + bv.y * w1 + bv.z * w2 + bv.w * w3;
      }
    }
  }

  // ---- phase A: e-dot, edge RMW, msg accumulate ----
  float wt[32];
  {
    const float* WeP = Wedge + (size_t)((lvl * 4 + lidx) * 32) * 32 + c;
    #pragma unroll
    for (int d = 0; d < 32; d++) wt[d] = WeP[d * 32];
  }
  float msg[7];
  #pragma unroll
  for (int m = 0; m < 7; m++) msg[m] = 0.f;

  #pragma unroll 2
  for (int jj = 0; jj < 32; jj++) {
    int j = jh * 32 + jj;
    float e0 = 0.f, e1 = 0.f;
    const float* sp = &sS[j][0];
    #pragma unroll
    for (int d0 = 0; d0 < 32; d0 += 4) {
      const float4 sv = *(const float4*)&sp[d0];
      e0 += sv.x * wt[d0] + sv.z * wt[d0 + 2];
      e1 += sv.y * wt[d0 + 1] + sv.w * wt[d0 + 3];
    }
    float e = e0 + e1;
    int eidx = ((row * 64 + j) * 4 + lidx) * 32 + c;
    if (lvl > 0) e += edge[eidx];
    float val = sCut[j] * rad[jj] * e;
    edge[eidx] = val;
    #pragma unroll
    for (int m = 0; m < 7; m++) msg[m] += val * sSphP[lidx][m][j];
  }

  // ---- phase B: reduce msg over jh ----
  #pragma unroll
  for (int m = 0; m < 7; m++) sMsgB[jh][lidx][m][c] = msg[m];
  __syncthreads();
  for (int o = tid; o < 512; o += 256) {
    int lm = o >> 5, cc = o & 31;
    int l = (lm == 0) ? 0 : (lm < 4) ? 1 : (lm < 9) ? 2 : 3;
    int bs = (l == 0) ? 0 : (l == 1) ? 1 : (l == 2) ? 4 : 9;
    int m = lm - bs;
    sMsgS[lm][cc] = sMsgB[0][l][m][cc] + sMsgB[1][l][m][cc];
  }
  __syncthreads();

  // ---- phase C: rep_new = msg@W_agg + rep_prev@W_self ----
  int d = tid & 31, lmg = tid >> 5;
  #pragma unroll
  for (int t = 0; t < 2; t++) {
    int lm = lmg + t * 8;
    int l = (lm == 0) ? 0 : (lm < 4) ? 1 : (lm < 9) ? 2 : 3;
    const float* Wa = Wagg + (lvl * 4 + l) * 32 * 32;     // [c][d]
    const float* Ws = Wself + (lvl * 4 + l) * 32 * 32;
    float acc = 0.f;
    for (int cc = 0; cc < 32; cc++) {
      acc += sMsgS[lm][cc] * Wa[cc * 32 + d];
      acc += repPrev[(row * 16 + lm) * 32 + cc] * Ws[cc * 32 + d];
    }
    repNext[(row * 16 + lm) * 32 + d] = acc;
  }
}

// ---------------- F1: per-atom invariant scalars . W_top -> partial ---------
__global__ void k_scalars(const float* __restrict__ repAll, const float* __restrict__ Wtop,
                          float* __restrict__ partial) {
  int an = blockIdx.x;                  // b*64 + n, 1024 blocks
  int tid = threadIdx.x;                // 128 threads
  __shared__ float red[128];
  float p = 0.f;
  for (int f = tid; f < 512; f += 128) {
    int lvl = f >> 7;
    int rem = f & 127;
    int l = rem >> 5;
    int c = rem & 31;
    const float* repB = repAll + (lvl + 1) * REPSZ + an * 512;   // [16][32] block
    int base = (l == 0) ? 0 : (l == 1) ? 1 : (l == 2) ? 4 : 9;
    float v;
    if (l == 0) {
      v = repB[c];
    } else {
      float s2 = 0.f;
      for (int m = 0; m < 2 * l + 1; m++) {
        float t = repB[(base + m) * 32 + c];
        s2 += t * t;
      }
      v = sqrtf(s2 + 1e-12f);
    }
    p += v * Wtop[f];
  }
  red[tid] = p;
  __syncthreads();
  for (int s = 64; s > 0; s >>= 1) {
    if (tid < s) red[tid] += red[tid + s];
    __syncthreads();
  }
  if (tid == 0) partial[an] = red[0];
}

// ---------------- F2: reduce partials per batch -----------------------------
__global__ void k_out(const float* __restrict__ partial, const float* __restrict__ btop,
                      float* __restrict__ out) {
  int b = blockIdx.x;                   // 16 blocks x 64 threads (1 wave)
  int tid = threadIdx.x;
  float v = partial[b * 64 + tid];
  #pragma unroll
  for (int o = 32; o > 0; o >>= 1) v += __shfl_down(v, o, 64);
  if (tid == 0) out[b] = v + btop[0];
}

// ---------------- launch ----------------------------------------------------
extern "C" void kernel_launch(void* const* d_in, const int* in_sizes, int n_in,
                              void* d_out, int out_size, void* d_ws, size_t ws_size,
                              hipStream_t stream) {
  const float* positions = (const float*)d_in[0];
  const float* one_hot   = (const float*)d_in[1];
  const int*   charges   = (const int*)d_in[2];
  const float* W_in   = (const float*)d_in[5];
  const float* b_in   = (const float*)d_in[6];
  const float* W_rad  = (const float*)d_in[7];
  const float* W_edge = (const float*)d_in[8];
  const float* W_agg  = (const float*)d_in[9];
  const float* W_self = (const float*)d_in[10];
  const float* W_top  = (const float*)d_in[11];
  const float* b_top  = (const float*)d_in[12];
  float* out = (float*)d_out;
  float* ws = (float*)d_ws;

  float* rep    = ws + OFF_REP;
  float* edge   = ws + OFF_EDGE;
  float* cutp   = ws + OFF_CUT;
  float* sphp   = ws + OFF_SPH;
  float* basisp = ws + OFF_BASIS;
  float* partial = ws + OFF_PART;   // aliases edge (dead after levels)

  k_init<<<2048, 256, 0, stream>>>(one_hot, charges, W_in, b_in, rep);
  k_geom<<<1024, 64, 0, stream>>>(positions, cutp, sphp, basisp);
  for (int lvl = 0; lvl < NLVL; lvl++) {
    k_level2<<<1024, 256, 0, stream>>>(lvl, W_rad, W_edge, W_agg, W_self,
                                       rep + lvl * REPSZ, rep + (lvl + 1) * REPSZ,
                                       edge, cutp, sphp, basisp);
  }
  k_scalars<<<1024, 128, 0, stream>>>(rep, W_top, partial);
  k_out<<<16, 64, 0, stream>>>(partial, b_top, out);
}